// Round 5
// baseline (290.044 us; speedup 1.0000x reference)
//
#include <hip/hip_runtime.h>
#include <stdint.h>
#include <stddef.h>

// ---------------------------------------------------------------------------
// SelfAttention: out = softmax((x W1^T + b1)(x W2^T + b2)^T) (x W2^T + b2)
// B=4, L=2048, D=1024. fp32 in/out; fp16 MFMA internals.
// Round 5 vs round 4 (269 us): occupancy is the binding resource (all pipes
// <30% busy, ~3 blocks/CU resident). Shrink tiles to double residency:
//   score 128x64 (grid 2048), out 64x128 (grid 1024, was 512 = 2/CU!),
//   proj 64x64 dual (grid 2048). XOR swizzle kept everywhere (r3: 4.2e6->0).
// ---------------------------------------------------------------------------

typedef _Float16  f16_t;
typedef _Float16  f16x8 __attribute__((ext_vector_type(8)));
typedef float     f32x4 __attribute__((ext_vector_type(4)));

__device__ __forceinline__ f32x4 mfma16(f16x8 a, f16x8 b, f32x4 c) {
  return __builtin_amdgcn_mfma_f32_16x16x32_f16(a, b, c, 0, 0, 0);
}

__device__ __forceinline__ void async_copy16(const f16_t* g, f16_t* l) {
  __builtin_amdgcn_global_load_lds(
      (const __attribute__((address_space(1))) unsigned int*)(g),
      (__attribute__((address_space(3))) unsigned int*)(l),
      16, 0, 0);
}

// C = A * B^T on a (RM*32) x (RN*32) tile, K = nk*32 contiguous in both.
// 4 waves in 2x2; wave quadrant (RM*16) x (RN*16). LDS [row][32] with the
// four 16B k-chunks of each row XOR-swizzled by (row>>1)&3 (conflict-free).
template <int RM, int RN>
__device__ __forceinline__ void gemm_core(
    const f16_t* __restrict__ A, const f16_t* __restrict__ B,
    int lda, int ldb, int nk,
    f16_t* __restrict__ As, f16_t* __restrict__ Bs, f32x4 (&acc)[RM][RN])
{
  const int tid  = threadIdx.x;
  const int lane = tid & 63;
  const int w    = tid >> 6;
  const int wr   = (w >> 1) * (RM * 16);
  const int wc   = (w & 1) * (RN * 16);
  const int l16  = lane & 15;
  const int quad = lane >> 4;
  const int sw   = (quad ^ ((l16 >> 1) & 3)) * 8;

  const int r0  = tid >> 2;
  const int kc0 = ((tid & 3) ^ ((r0 >> 1) & 3)) * 8;

  const f16_t* Ag = A + (size_t)r0 * lda + kc0;
  const f16_t* Bg = B + (size_t)r0 * ldb + kc0;

  for (int kt = 0; kt < nk; ++kt) {
#pragma unroll
    for (int h = 0; h < RM / 2; ++h)
      async_copy16(Ag + (size_t)(64 * h) * lda, As + (tid + 256 * h) * 8);
#pragma unroll
    for (int h = 0; h < RN / 2; ++h)
      async_copy16(Bg + (size_t)(64 * h) * ldb, Bs + (tid + 256 * h) * 8);
    __syncthreads();

    f16x8 af[RM], bf[RN];
#pragma unroll
    for (int i = 0; i < RM; ++i)
      af[i] = *(const f16x8*)(As + (wr + i * 16 + l16) * 32 + sw);
#pragma unroll
    for (int j = 0; j < RN; ++j)
      bf[j] = *(const f16x8*)(Bs + (wc + j * 16 + l16) * 32 + sw);
#pragma unroll
    for (int i = 0; i < RM; ++i)
#pragma unroll
      for (int j = 0; j < RN; ++j)
        acc[i][j] = mfma16(af[i], bf[j], acc[i][j]);

    __syncthreads();
    Ag += 32; Bg += 32;
  }
}

// ---------------------------------------------------------------------------
// 0) fp32 -> fp16 converter, 8 elems/thread.
__global__ __launch_bounds__(256) void cvt_kernel(
    const float* __restrict__ in, f16_t* __restrict__ out)
{
  const size_t i = ((size_t)blockIdx.x * 256 + threadIdx.x) * 8;
  f32x4 a = *(const f32x4*)(in + i);
  f32x4 b = *(const f32x4*)(in + i + 4);
  f16x8 o;
#pragma unroll
  for (int k = 0; k < 4; ++k) { o[k] = (f16_t)a[k]; o[k + 4] = (f16_t)b[k]; }
  *(f16x8*)(out + i) = o;
}

// ---------------------------------------------------------------------------
// 1) fused projection, 64x64 tiles: Q = xW1^T+b1, V = xW2^T+b2 (fp16).
//    x tile (64x32) staged once per iter for both GEMMs. Grid 128x16=2048,
//    ~8 blocks/CU. Wave quadrant 32x32, accQ/accV [2][2].
__global__ __launch_bounds__(256) void proj_qv_kernel(
    const f16_t* __restrict__ X, const f16_t* __restrict__ W1,
    const f16_t* __restrict__ W2, const float* __restrict__ b1,
    const float* __restrict__ b2, f16_t* __restrict__ Q,
    f16_t* __restrict__ V)
{
  __shared__ __align__(16) f16_t Xs[64 * 32];    // 4 KB
  __shared__ __align__(16) f16_t W1s[64 * 32];   // 4 KB
  __shared__ __align__(16) f16_t W2s[64 * 32];   // 4 KB

  const int m0 = blockIdx.x * 64;
  const int n0 = blockIdx.y * 64;

  const int tid  = threadIdx.x;
  const int lane = tid & 63;
  const int w    = tid >> 6;
  const int wr   = (w >> 1) * 32;
  const int wc   = (w & 1) * 32;
  const int quad = lane >> 4;
  const int l16  = lane & 15;
  const int sw   = (quad ^ ((l16 >> 1) & 3)) * 8;
  const int r0   = tid >> 2;
  const int kc0  = ((tid & 3) ^ ((r0 >> 1) & 3)) * 8;

  const f16_t* Xg = X + (size_t)(m0 + r0) * 1024 + kc0;
  const f16_t* G1 = W1 + (size_t)(n0 + r0) * 1024 + kc0;
  const f16_t* G2 = W2 + (size_t)(n0 + r0) * 1024 + kc0;

  f32x4 accQ[2][2] = {};
  f32x4 accV[2][2] = {};

  for (int kt = 0; kt < 32; ++kt) {
    async_copy16(Xg, Xs + tid * 8);
    async_copy16(G1, W1s + tid * 8);
    async_copy16(G2, W2s + tid * 8);
    __syncthreads();

    f16x8 xf[2], w1f[2], w2f[2];
#pragma unroll
    for (int i = 0; i < 2; ++i) {
      xf[i]  = *(const f16x8*)(Xs  + (wr + i * 16 + l16) * 32 + sw);
      w1f[i] = *(const f16x8*)(W1s + (wc + i * 16 + l16) * 32 + sw);
      w2f[i] = *(const f16x8*)(W2s + (wc + i * 16 + l16) * 32 + sw);
    }
#pragma unroll
    for (int i = 0; i < 2; ++i)
#pragma unroll
      for (int j = 0; j < 2; ++j) {
        accQ[i][j] = mfma16(xf[i], w1f[j], accQ[i][j]);
        accV[i][j] = mfma16(xf[i], w2f[j], accV[i][j]);
      }
    __syncthreads();
    Xg += 32; G1 += 32; G2 += 32;
  }

#pragma unroll
  for (int j = 0; j < 2; ++j) {
    const int col = n0 + wc + j * 16 + l16;
    const float bq = b1[col], bv = b2[col];
#pragma unroll
    for (int i = 0; i < 2; ++i)
#pragma unroll
      for (int r = 0; r < 4; ++r) {
        const int row = m0 + wr + i * 16 + quad * 4 + r;
        Q[(size_t)row * 1024 + col] = (f16_t)(accQ[i][j][r] + bq);
        V[(size_t)row * 1024 + col] = (f16_t)(accV[i][j][r] + bv);
      }
  }
}

// ---------------------------------------------------------------------------
// 1b) Vt[b][d][key] = V[b][key][d]. 64x64 tiles through LDS, XOR-swizzled,
//     conflict-free, coalesced both sides. Grid (32 key, 16 d, 4 b).
__global__ __launch_bounds__(256) void vt_kernel(
    const f16_t* __restrict__ V, f16_t* __restrict__ Vt)
{
  __shared__ __align__(16) f16_t Ls[64 * 64];   // 8 KB
  const int key0 = blockIdx.x * 64;
  const int d0   = blockIdx.y * 64;
  const size_t boff = (size_t)blockIdx.z * 2048 * 1024;

  const int tid = threadIdx.x;
#pragma unroll
  for (int rep = 0; rep < 2; ++rep) {
    const int kr = rep * 32 + (tid >> 3);
    const int dc = (tid & 7) * 8;
    f16x8 v = *(const f16x8*)(V + boff + (size_t)(key0 + kr) * 1024 + d0 + dc);
#pragma unroll
    for (int e = 0; e < 8; ++e) {
      const int d = dc + e;
      Ls[d * 64 + (((kr >> 3) ^ (d >> 3)) << 3) + (kr & 7)] = v[e];
    }
  }
  __syncthreads();
#pragma unroll
  for (int rep = 0; rep < 2; ++rep) {
    const int d = rep * 32 + (tid >> 3);
    const int c = tid & 7;
    f16x8 v = *(const f16x8*)(Ls + d * 64 + ((c ^ (d >> 3)) << 3));
    *(f16x8*)(Vt + boff + (size_t)(d0 + d) * 2048 + key0 + c * 8) = v;
  }
}

// ---------------------------------------------------------------------------
// 2) scores: S[b][q][k] = Q[b,q,:] . V[b,k,:] (fp32). 128x64 tile,
//    grid 16x32x4 = 2048 blocks (~6 blocks/CU).
__global__ __launch_bounds__(256) void score_kernel(
    const f16_t* __restrict__ Q, const f16_t* __restrict__ V,
    float* __restrict__ S)
{
  __shared__ __align__(16) f16_t As[128 * 32];   // 8 KB
  __shared__ __align__(16) f16_t Bs[64 * 32];    // 4 KB
  const int m0 = blockIdx.x * 128;
  const int n0 = blockIdx.y * 64;
  const size_t boff = (size_t)blockIdx.z * 2048 * 1024;

  f32x4 acc[4][2] = {};
  gemm_core<4, 2>(Q + boff + (size_t)m0 * 1024, V + boff + (size_t)n0 * 1024,
                  1024, 1024, 1024 / 32, As, Bs, acc);

  float* Sb = S + (size_t)blockIdx.z * 2048 * 2048;
  const int lane = threadIdx.x & 63;
  const int w    = threadIdx.x >> 6;
  const int wr   = (w >> 1) * 64, wc = (w & 1) * 32;
  const int quad = lane >> 4,     l16 = lane & 15;

#pragma unroll
  for (int i = 0; i < 4; ++i)
#pragma unroll
    for (int j = 0; j < 2; ++j)
#pragma unroll
      for (int r = 0; r < 4; ++r) {
        const int row = m0 + wr + i * 16 + quad * 4 + r;
        const int col = n0 + wc + j * 16 + l16;
        Sb[(size_t)row * 2048 + col] = acc[i][j][r];
      }
}

// ---------------------------------------------------------------------------
// 3) softmax over each 2048-fp32 row of S; fp16 P written in-place.
__global__ __launch_bounds__(256) void softmax_kernel(float* __restrict__ S)
{
  float* src = S + (size_t)blockIdx.x * 2048;
  f16_t* dst = (f16_t*)src;
  const int tid  = threadIdx.x;
  const int lane = tid & 63;
  const int w    = tid >> 6;

  f32x4 va = *((const f32x4*)src + tid * 2);
  f32x4 vb = *((const f32x4*)src + tid * 2 + 1);
  float f[8];
#pragma unroll
  for (int k = 0; k < 4; ++k) { f[k] = va[k]; f[k + 4] = vb[k]; }

  float m = f[0];
#pragma unroll
  for (int k = 1; k < 8; ++k) m = fmaxf(m, f[k]);
#pragma unroll
  for (int off = 32; off >= 1; off >>= 1) m = fmaxf(m, __shfl_xor(m, off));

  __shared__ float red[4];
  if (lane == 0) red[w] = m;
  __syncthreads();
  m = fmaxf(fmaxf(red[0], red[1]), fmaxf(red[2], red[3]));

  float s = 0.f;
#pragma unroll
  for (int k = 0; k < 8; ++k) { f[k] = __expf(f[k] - m); s += f[k]; }
#pragma unroll
  for (int off = 32; off >= 1; off >>= 1) s += __shfl_xor(s, off);
  __syncthreads();
  if (lane == 0) red[w] = s;
  __syncthreads();
  s = (red[0] + red[1]) + (red[2] + red[3]);
  const float inv = 1.f / s;

  f16x8 o;
#pragma unroll
  for (int k = 0; k < 8; ++k) o[k] = (f16_t)(f[k] * inv);
  *((f16x8*)dst + tid) = o;
}

// ---------------------------------------------------------------------------
// 4) out[b][q][d] = sum_k P[b][q][k] * Vt[b][d][k] -> fp32. P pitch 4096 f16.
//    64x128 tile, grid 32x8x4 = 1024 blocks (4/CU, was 2/CU).
__global__ __launch_bounds__(256) void out_kernel(
    const f16_t* __restrict__ P, const f16_t* __restrict__ Vt,
    float* __restrict__ Out)
{
  __shared__ __align__(16) f16_t As[64 * 32];    // 4 KB
  __shared__ __align__(16) f16_t Bs[128 * 32];   // 8 KB
  const int m0 = blockIdx.x * 64;
  const int n0 = blockIdx.y * 128;
  const size_t poff  = (size_t)blockIdx.z * 2048 * 4096;
  const size_t vtoff = (size_t)blockIdx.z * 1024 * 2048;

  f32x4 acc[2][4] = {};
  gemm_core<2, 4>(P + poff + (size_t)m0 * 4096, Vt + vtoff + (size_t)n0 * 2048,
                  4096, 2048, 2048 / 32, As, Bs, acc);

  float* Ob = Out + (size_t)blockIdx.z * 2048 * 1024;
  const int lane = threadIdx.x & 63;
  const int w    = threadIdx.x >> 6;
  const int wr   = (w >> 1) * 32, wc = (w & 1) * 64;
  const int quad = lane >> 4,     l16 = lane & 15;

#pragma unroll
  for (int i = 0; i < 2; ++i)
#pragma unroll
    for (int j = 0; j < 4; ++j)
#pragma unroll
      for (int r = 0; r < 4; ++r) {
        const int row = m0 + wr + i * 16 + quad * 4 + r;
        const int col = n0 + wc + j * 16 + l16;
        Ob[(size_t)row * 1024 + col] = acc[i][j][r];
      }
}

// ---------------------------------------------------------------------------
extern "C" void kernel_launch(void* const* d_in, const int* in_sizes, int n_in,
                              void* d_out, int out_size, void* d_ws, size_t ws_size,
                              hipStream_t stream) {
  const float* x  = (const float*)d_in[0];
  const float* W1 = (const float*)d_in[1];
  const float* b1 = (const float*)d_in[2];
  const float* W2 = (const float*)d_in[3];
  const float* b2 = (const float*)d_in[4];
  float* out = (float*)d_out;

  const size_t QN = (size_t)8192 * 1024;
  const size_t WN = (size_t)1024 * 1024;
  f16_t* xh  = (f16_t*)d_ws;       // 16 MiB
  f16_t* W1h = xh + QN;            //  2 MiB
  f16_t* W2h = W1h + WN;           //  2 MiB
  f16_t* Q   = W2h + WN;           // 16 MiB
  f16_t* V   = Q + QN;             // 16 MiB
  f16_t* Vt  = V + QN;             // 16 MiB [4][1024][2048]
  float* S   = (float*)(Vt + QN);  // 64 MiB [4][2048][2048], P fp16 in-place

  dim3 blk(256);
  cvt_kernel<<<4096, blk, 0, stream>>>(x, xh);
  cvt_kernel<<<512, blk, 0, stream>>>(W1, W1h);
  cvt_kernel<<<512, blk, 0, stream>>>(W2, W2h);
  proj_qv_kernel<<<dim3(128, 16), blk, 0, stream>>>(xh, W1h, W2h, b1, b2, Q, V);
  vt_kernel<<<dim3(32, 16, 4), blk, 0, stream>>>(V, Vt);
  score_kernel<<<dim3(16, 32, 4), blk, 0, stream>>>(Q, V, S);
  softmax_kernel<<<8192, blk, 0, stream>>>(S);
  out_kernel<<<dim3(32, 8, 4), blk, 0, stream>>>((const f16_t*)S, Vt, out);
}